// Round 3
// baseline (31085.233 us; speedup 1.0000x reference)
//
#include <hip/hip_runtime.h>
#include <hip/hip_bf16.h>

typedef __bf16 bf16_t;
typedef bf16_t bf16x8 __attribute__((ext_vector_type(8)));
typedef float  f32x4  __attribute__((ext_vector_type(4)));

#define NB 64      // batch
#define NS 256     // seq len
#define NH 1024    // hidden
#define NL 4       // layers
#define G3H 3072   // 3*H

__device__ __forceinline__ f32x4 mfma16(bf16x8 a, bf16x8 b, f32x4 c) {
    return __builtin_amdgcn_mfma_f32_16x16x32_bf16(a, b, c, 0, 0, 0);
}

__device__ __forceinline__ float sigmoidf_(float x) {
    return 1.0f / (1.0f + expf(-x));
}

struct P {
    const float* x;        // (B,S,H)
    const float* b_ih;     // (L,3H)
    const float* b_hh;     // (L,3H)
    float* out;            // outs (B,S,H) then hT (L,B,H)
    const bf16_t* Wih;     // (L,3H,H)
    const bf16_t* Whh;
    const bf16_t* w0;      // (L,H,H)
    const bf16_t* w1;      // (L,512,512)
    const bf16_t* w2;      // (L,512,512)
    const bf16_t* w3;      // (L,H,2H)
    float*  h_fp;          // (L,B,H) hidden state fp32
    bf16_t* h_bf;          // (L,B,H)
    float*  hprime;        // (L,B,H) GRU output pre-attn
    bf16_t* se;            // (L,B,2,H)  row0=h', row1=sorted(h')
    bf16_t* sA0;           // (L,B,2048) shuffled a0
    bf16_t* sA1;           // (L,B,2048) shuffled a1
    bf16_t* a2;            // (L,B,2048) relu(a2) flat
    bf16_t* outbuf;        // (2,L,B,H)  inter-layer input, dbuf by t parity
};

struct ConvArgs {
    const float* src[6];
    bf16_t* dst[6];
    long n[6];
    const float* hidden0;  // (L,1,H)
    float* h_fp;
    bf16_t* h_bf;
};

__global__ void __launch_bounds__(256) convert_kernel(ConvArgs a) {
    const long tid = (long)blockIdx.x * 256 + threadIdx.x;
    const long stride = (long)gridDim.x * 256;
    for (int i = 0; i < 6; ++i) {
        const float* s = a.src[i];
        bf16_t* d = a.dst[i];
        const long n = a.n[i];
        for (long j = tid * 4; j < n; j += stride * 4) {
            float4 v = *(const float4*)(s + j);
            d[j + 0] = (bf16_t)v.x;
            d[j + 1] = (bf16_t)v.y;
            d[j + 2] = (bf16_t)v.z;
            d[j + 3] = (bf16_t)v.w;
        }
    }
    for (long j = tid; j < (long)NL * NB * NH; j += stride) {
        int l = (int)(j >> 16);           // B*H = 65536
        int c = (int)(j & (NH - 1));
        float v = a.hidden0[l * NH + c];
        a.h_fp[j] = v;
        a.h_bf[j] = (bf16_t)v;
    }
}

// ---------- S1: GRU  gi = inp@Wih^T, gh = h@Whh^T, gates, h' ----------
__global__ void __launch_bounds__(256) k_gru(P p, int s) {
    const int l = blockIdx.x >> 6;
    const int t = s - l;
    if (t < 0 || t >= NS) return;
    const int wj = blockIdx.x & 63;
    const int tid = threadIdx.x;
    const int wave = tid >> 6, lane = tid & 63;
    const int lane15 = lane & 15, quad = lane >> 4, kq = quad * 8;

    const bf16_t* Wih_l = p.Wih + (size_t)l * G3H * NH;
    const bf16_t* Whh_l = p.Whh + (size_t)l * G3H * NH;
    const float* bih_l = p.b_ih + l * G3H;
    const float* bhh_l = p.b_hh + l * G3H;
    const float*  hfp_l = p.h_fp + (size_t)l * NB * NH;
    const bf16_t* hbf_l = p.h_bf + (size_t)l * NB * NH;
    float*  hpr_l = p.hprime + (size_t)l * NB * NH;
    bf16_t* se_l  = p.se + (size_t)l * 2 * NB * NH;

    const int c0 = wj * 16;          // hidden column block
    const int m0 = wave * 16;        // batch row stripe
    const int arow = m0 + lane15;    // A-fragment row (batch)
    const bf16_t* inp_l = (l > 0)
        ? (p.outbuf + ((size_t)(t & 1) * NL + (l - 1)) * NB * NH) : nullptr;
    const float* xrow = p.x + ((size_t)arow * NS + t) * NH;

    f32x4 acc[6] = {};
    for (int k0 = 0; k0 < NH; k0 += 32) {
        const int k = k0 + kq;
        bf16x8 a_i;
        if (l == 0) {
            float4 f0 = *(const float4*)(xrow + k);
            float4 f1 = *(const float4*)(xrow + k + 4);
            a_i[0] = (bf16_t)f0.x; a_i[1] = (bf16_t)f0.y;
            a_i[2] = (bf16_t)f0.z; a_i[3] = (bf16_t)f0.w;
            a_i[4] = (bf16_t)f1.x; a_i[5] = (bf16_t)f1.y;
            a_i[6] = (bf16_t)f1.z; a_i[7] = (bf16_t)f1.w;
        } else {
            a_i = *(const bf16x8*)(inp_l + (size_t)arow * NH + k);
        }
        bf16x8 a_h = *(const bf16x8*)(hbf_l + (size_t)arow * NH + k);
#pragma unroll
        for (int g = 0; g < 3; ++g) {
            bf16x8 bi = *(const bf16x8*)(Wih_l + (size_t)(g * NH + c0 + lane15) * NH + k);
            bf16x8 bh = *(const bf16x8*)(Whh_l + (size_t)(g * NH + c0 + lane15) * NH + k);
            acc[g]     = mfma16(a_i, bi, acc[g]);
            acc[3 + g] = mfma16(a_h, bh, acc[3 + g]);
        }
    }
    const int c = c0 + lane15;
#pragma unroll
    for (int i = 0; i < 4; ++i) {
        const int m = m0 + quad * 4 + i;
        float ir  = acc[0][i] + bih_l[c];
        float iz  = acc[1][i] + bih_l[NH + c];
        float inn = acc[2][i] + bih_l[2 * NH + c];
        float hr  = acc[3][i] + bhh_l[c];
        float hz  = acc[4][i] + bhh_l[NH + c];
        float hn  = acc[5][i] + bhh_l[2 * NH + c];
        float r = sigmoidf_(ir + hr);
        float z = sigmoidf_(iz + hz);
        float n = tanhf(inn + r * hn);
        float hprev = hfp_l[(size_t)m * NH + c];
        float hp = (1.0f - z) * n + z * hprev;
        hpr_l[(size_t)m * NH + c] = hp;
        se_l[(size_t)(m * 2) * NH + c] = (bf16_t)hp;   // se row 0 = h'
    }
}

// ---------- S2: sort h' rows (bitonic ascending) -> se row 1 ----------
__global__ void __launch_bounds__(256) k_sort(P p, int s) {
    const int l = blockIdx.x >> 6;
    const int t = s - l;
    if (t < 0 || t >= NS) return;
    const int b = blockIdx.x & 63;
    const int tid = threadIdx.x;
    const float* hpr_l = p.hprime + (size_t)l * NB * NH;
    bf16_t* se_l = p.se + (size_t)l * 2 * NB * NH;

    __shared__ float sbuf[NH];
    const float* src = hpr_l + (size_t)b * NH;
    for (int i = tid; i < NH; i += 256) sbuf[i] = src[i];
    __syncthreads();
    for (int kk = 2; kk <= NH; kk <<= 1) {
        for (int j = kk >> 1; j > 0; j >>= 1) {
#pragma unroll
            for (int bb = 0; bb < 4; ++bb) {
                const int i = bb * 256 + tid;
                const int ixj = i ^ j;
                if (ixj > i) {
                    float va = sbuf[i], vb = sbuf[ixj];
                    bool up = ((i & kk) == 0);
                    if (up ? (va > vb) : (va < vb)) {
                        sbuf[i] = vb; sbuf[ixj] = va;
                    }
                }
            }
            __syncthreads();
        }
    }
    bf16_t* dst = se_l + (size_t)(b * 2 + 1) * NH;
    for (int i = tid; i < NH; i += 256) dst[i] = (bf16_t)sbuf[i];
}

// ---------- S3: a0 = se@w0^T  (M=128,N=1024,K=1024), store shuffled ----------
__global__ void __launch_bounds__(256) k_a0(P p, int s) {
    const int l = blockIdx.x >> 6;
    const int t = s - l;
    if (t < 0 || t >= NS) return;
    const int wj = blockIdx.x & 63;
    const int tid = threadIdx.x;
    const int wave = tid >> 6, lane = tid & 63;
    const int lane15 = lane & 15, quad = lane >> 4, kq = quad * 8;
    const bf16_t* w0_l = p.w0 + (size_t)l * NH * NH;
    const bf16_t* se_l = p.se + (size_t)l * 2 * NB * NH;
    bf16_t* sA0_l = p.sA0 + (size_t)l * NB * 2048;

    const int mhalf = wj >> 5;
    const int c0 = (wj & 31) * 32;
    const int r0 = mhalf * 64 + wave * 16;
    f32x4 acc0 = {}, acc1 = {};
    for (int k0 = 0; k0 < NH; k0 += 32) {
        const int k = k0 + kq;
        bf16x8 a  = *(const bf16x8*)(se_l + (size_t)(r0 + lane15) * NH + k);
        bf16x8 b0 = *(const bf16x8*)(w0_l + (size_t)(c0 + lane15) * NH + k);
        bf16x8 b1 = *(const bf16x8*)(w0_l + (size_t)(c0 + 16 + lane15) * NH + k);
        acc0 = mfma16(a, b0, acc0);
        acc1 = mfma16(a, b1, acc1);
    }
#pragma unroll
    for (int i = 0; i < 4; ++i) {
        const int r = r0 + quad * 4 + i;   // 0..127 = b*2+tt
        const int bidx = r >> 1, tt = r & 1;
        const int o0 = c0 + lane15;
        const int j0 = tt * NH + o0;
        sA0_l[(size_t)bidx * 2048 + ((j0 & 511) * 4 + (j0 >> 9))] = (bf16_t)acc0[i];
        const int j1 = tt * NH + o0 + 16;
        sA0_l[(size_t)bidx * 2048 + ((j1 & 511) * 4 + (j1 >> 9))] = (bf16_t)acc1[i];
    }
}

// ---------- S4: a1 = sA0@w1^T (M=256,N=512,K=512), store shuffled ----------
__global__ void __launch_bounds__(256) k_a1(P p, int s) {
    const int l = blockIdx.x >> 6;
    const int t = s - l;
    if (t < 0 || t >= NS) return;
    const int wj = blockIdx.x & 63;
    const int tid = threadIdx.x;
    const int wave = tid >> 6, lane = tid & 63;
    const int lane15 = lane & 15, quad = lane >> 4, kq = quad * 8;
    const bf16_t* w1_l = p.w1 + (size_t)l * 512 * 512;
    const bf16_t* sA0_l = p.sA0 + (size_t)l * NB * 2048;
    bf16_t* sA1_l = p.sA1 + (size_t)l * NB * 2048;

    const int mblk = wj >> 4;
    const int c0 = (wj & 15) * 32;
    const int r0 = mblk * 64 + wave * 16;    // rows = b*4+g
    f32x4 acc0 = {}, acc1 = {};
    for (int k0 = 0; k0 < 512; k0 += 32) {
        const int k = k0 + kq;
        bf16x8 a  = *(const bf16x8*)(sA0_l + (size_t)(r0 + lane15) * 512 + k);
        bf16x8 b0 = *(const bf16x8*)(w1_l + (size_t)(c0 + lane15) * 512 + k);
        bf16x8 b1 = *(const bf16x8*)(w1_l + (size_t)(c0 + 16 + lane15) * 512 + k);
        acc0 = mfma16(a, b0, acc0);
        acc1 = mfma16(a, b1, acc1);
    }
#pragma unroll
    for (int i = 0; i < 4; ++i) {
        const int rr = r0 + quad * 4 + i;
        const int bidx = rr >> 2, g = rr & 3;
        const int o0 = c0 + lane15;
        sA1_l[(size_t)bidx * 2048 + o0 * 4 + g]        = (bf16_t)acc0[i];
        sA1_l[(size_t)bidx * 2048 + (o0 + 16) * 4 + g] = (bf16_t)acc1[i];
    }
}

// ---------- S5: a2 = relu(sA1@w2^T), store flat ----------
__global__ void __launch_bounds__(256) k_a2(P p, int s) {
    const int l = blockIdx.x >> 6;
    const int t = s - l;
    if (t < 0 || t >= NS) return;
    const int wj = blockIdx.x & 63;
    const int tid = threadIdx.x;
    const int wave = tid >> 6, lane = tid & 63;
    const int lane15 = lane & 15, quad = lane >> 4, kq = quad * 8;
    const bf16_t* w2_l = p.w2 + (size_t)l * 512 * 512;
    const bf16_t* sA1_l = p.sA1 + (size_t)l * NB * 2048;
    bf16_t* a2_l = p.a2 + (size_t)l * NB * 2048;

    const int mblk = wj >> 4;
    const int c0 = (wj & 15) * 32;
    const int r0 = mblk * 64 + wave * 16;
    f32x4 acc0 = {}, acc1 = {};
    for (int k0 = 0; k0 < 512; k0 += 32) {
        const int k = k0 + kq;
        bf16x8 a  = *(const bf16x8*)(sA1_l + (size_t)(r0 + lane15) * 512 + k);
        bf16x8 b0 = *(const bf16x8*)(w2_l + (size_t)(c0 + lane15) * 512 + k);
        bf16x8 b1 = *(const bf16x8*)(w2_l + (size_t)(c0 + 16 + lane15) * 512 + k);
        acc0 = mfma16(a, b0, acc0);
        acc1 = mfma16(a, b1, acc1);
    }
#pragma unroll
    for (int i = 0; i < 4; ++i) {
        const int rr = r0 + quad * 4 + i;       // b*4+g
        const int o0 = c0 + lane15;
        float v0 = acc0[i] > 0.0f ? acc0[i] : 0.0f;
        float v1 = acc1[i] > 0.0f ? acc1[i] : 0.0f;
        a2_l[(size_t)rr * 512 + o0]      = (bf16_t)v0;
        a2_l[(size_t)rr * 512 + o0 + 16] = (bf16_t)v1;
    }
}

// ---------- S6: a3 = a2@w3^T (M=64,N=1024,K=2048); h = h'*sigmoid(a3) ----------
__global__ void __launch_bounds__(256) k_a3(P p, int s) {
    const int l = blockIdx.x >> 6;
    const int t = s - l;
    if (t < 0 || t >= NS) return;
    const int wj = blockIdx.x & 63;
    const int tid = threadIdx.x;
    const int wave = tid >> 6, lane = tid & 63;
    const int lane15 = lane & 15, quad = lane >> 4, kq = quad * 8;
    const bf16_t* w3_l = p.w3 + (size_t)l * NH * 2048;
    const bf16_t* a2_l = p.a2 + (size_t)l * NB * 2048;
    const float* hpr_l = p.hprime + (size_t)l * NB * NH;
    float*  hfp_l = p.h_fp + (size_t)l * NB * NH;
    bf16_t* hbf_l = p.h_bf + (size_t)l * NB * NH;

    const int c0 = wj * 16;
    const int m0 = wave * 16;
    f32x4 acc = {};
    for (int k0 = 0; k0 < 2048; k0 += 32) {
        const int k = k0 + kq;
        bf16x8 a = *(const bf16x8*)(a2_l + (size_t)(m0 + lane15) * 2048 + k);
        bf16x8 b = *(const bf16x8*)(w3_l + (size_t)(c0 + lane15) * 2048 + k);
        acc = mfma16(a, b, acc);
    }
    const int c = c0 + lane15;
    bf16_t* ob = (l < NL - 1)
        ? (p.outbuf + ((size_t)(t & 1) * NL + l) * NB * NH) : nullptr;
#pragma unroll
    for (int i = 0; i < 4; ++i) {
        const int m = m0 + quad * 4 + i;
        float sg = sigmoidf_(acc[i]);
        float val = hpr_l[(size_t)m * NH + c] * sg;
        hfp_l[(size_t)m * NH + c] = val;
        hbf_l[(size_t)m * NH + c] = (bf16_t)val;
        if (l < NL - 1) {
            ob[(size_t)m * NH + c] = (bf16_t)val;
        } else {
            p.out[((size_t)m * NS + t) * NH + c] = val;   // outs (B,S,H)
        }
        if (t == NS - 1) {
            p.out[(size_t)NB * NS * NH + ((size_t)l * NB + m) * NH + c] = val;  // hT
        }
    }
}

extern "C" void kernel_launch(void* const* d_in, const int* in_sizes, int n_in,
                              void* d_out, int out_size, void* d_ws, size_t ws_size,
                              hipStream_t stream) {
    const float* x       = (const float*)d_in[0];
    const float* hidden0 = (const float*)d_in[1];
    const float* Wih_f   = (const float*)d_in[2];
    const float* Whh_f   = (const float*)d_in[3];
    const float* bih     = (const float*)d_in[4];
    const float* bhh     = (const float*)d_in[5];
    const float* aw0     = (const float*)d_in[6];
    const float* aw1     = (const float*)d_in[7];
    const float* aw2     = (const float*)d_in[8];
    const float* aw3     = (const float*)d_in[9];

    char* ws = (char*)d_ws;
    size_t off = 0;
    auto alloc = [&](size_t bytes) -> void* {
        void* r = ws + off;
        off = (off + bytes + 255) & ~(size_t)255;
        return r;
    };

    const long nWih = (long)NL * G3H * NH;
    const long nWhh = (long)NL * G3H * NH;
    const long nw0  = (long)NL * NH * NH;
    const long nw1  = (long)NL * 512 * 512;
    const long nw2  = (long)NL * 512 * 512;
    const long nw3  = (long)NL * NH * 2048;

    P p;
    p.x = x; p.b_ih = bih; p.b_hh = bhh; p.out = (float*)d_out;
    p.Wih = (bf16_t*)alloc((size_t)nWih * 2);
    p.Whh = (bf16_t*)alloc((size_t)nWhh * 2);
    p.w0  = (bf16_t*)alloc((size_t)nw0 * 2);
    p.w1  = (bf16_t*)alloc((size_t)nw1 * 2);
    p.w2  = (bf16_t*)alloc((size_t)nw2 * 2);
    p.w3  = (bf16_t*)alloc((size_t)nw3 * 2);
    p.h_fp   = (float*) alloc((size_t)NL * NB * NH * 4);
    p.h_bf   = (bf16_t*)alloc((size_t)NL * NB * NH * 2);
    p.hprime = (float*) alloc((size_t)NL * NB * NH * 4);
    p.se     = (bf16_t*)alloc((size_t)NL * 2 * NB * NH * 2);
    p.sA0    = (bf16_t*)alloc((size_t)NL * NB * 2048 * 2);
    p.sA1    = (bf16_t*)alloc((size_t)NL * NB * 2048 * 2);
    p.a2     = (bf16_t*)alloc((size_t)NL * NB * 2048 * 2);
    p.outbuf = (bf16_t*)alloc((size_t)2 * NL * NB * NH * 2);

    ConvArgs ca;
    ca.src[0] = Wih_f; ca.dst[0] = (bf16_t*)p.Wih; ca.n[0] = nWih;
    ca.src[1] = Whh_f; ca.dst[1] = (bf16_t*)p.Whh; ca.n[1] = nWhh;
    ca.src[2] = aw0;   ca.dst[2] = (bf16_t*)p.w0;  ca.n[2] = nw0;
    ca.src[3] = aw1;   ca.dst[3] = (bf16_t*)p.w1;  ca.n[3] = nw1;
    ca.src[4] = aw2;   ca.dst[4] = (bf16_t*)p.w2;  ca.n[4] = nw2;
    ca.src[5] = aw3;   ca.dst[5] = (bf16_t*)p.w3;  ca.n[5] = nw3;
    ca.hidden0 = hidden0;
    ca.h_fp = p.h_fp;
    ca.h_bf = p.h_bf;

    convert_kernel<<<dim3(2048), dim3(256), 0, stream>>>(ca);

    for (int s = 0; s < NS + NL - 1; ++s) {
        k_gru <<<dim3(NL * 64), dim3(256), 0, stream>>>(p, s);
        k_sort<<<dim3(NL * 64), dim3(256), 0, stream>>>(p, s);
        k_a0  <<<dim3(NL * 64), dim3(256), 0, stream>>>(p, s);
        k_a1  <<<dim3(NL * 64), dim3(256), 0, stream>>>(p, s);
        k_a2  <<<dim3(NL * 64), dim3(256), 0, stream>>>(p, s);
        k_a3  <<<dim3(NL * 64), dim3(256), 0, stream>>>(p, s);
    }
}